// Round 3
// baseline (296.362 us; speedup 1.0000x reference)
//
#include <hip/hip_runtime.h>

// 3x3 valid conv (NCHW/OIHW) + bias + relu(y)*min(y+3,6)/6, fp32.
// x: (N=4096, C=3, 32, 32), w: (16, 3, 3, 3), out: (N, 16, 30, 30).
//
// Round 7 design (vs R6, conv ~139us inferred):
//  - R4/R6 invariance at ~140us despite different weight paths + store
//    patterns => stall/latency-bound, not pipe-bound (clean-count: FMA 28us,
//    LDS 17us, HBM 45us per-CU/chip). OccupancyPercent was ~49%: the 64
//    accumulators of 4px/thread put every prior round in the (64,128] VGPR
//    band -> hard 16 waves/CU cap (occupancy steps at 64/128/256).
//  - Fix: 512 threads x 2 px/thread -> acc[2][16] = 32 VGPRs, target total
//    <= 64 -> __launch_bounds__(512,8) = 32 waves/CU (100%). Doubled
//    latency hiding on LDS reads, s_load waits, barrier drains, staging.
//  - Keep what worked: scalar-path weights/bias (SGPR, v_fmac v,s,v),
//    12KB sx image staging, LDS-transposed epilogue with aligned float4
//    stores (full 64B lines, no write amplification).
//  - LDS 28KB -> 4 blocks/CU fits (112KB < 160KB).

__global__ __launch_bounds__(512, 8) void conv3x3_hswish(
    const float* __restrict__ x,
    const float* __restrict__ w,
    const float* __restrict__ bias,
    float* __restrict__ out)
{
    const int n = blockIdx.x;
    const int tid = threadIdx.x;   // 0..511

    __shared__ __align__(16) float sx[3072];   // image, 12 KB
    __shared__ __align__(16) float sy[4096];   // epilogue staging, 16 KB

    // Stage image: 768 float4s, coalesced.
    {
        const float4* xg = (const float4*)(x + (size_t)n * 3072);
        float4* s4 = (float4*)sx;
        s4[tid] = xg[tid];
        if (tid < 256) s4[tid + 512] = xg[tid + 512];
    }
    __syncthreads();

    // Pixel k of this thread: p = tid + k*512 (flattened oh*30+ow), <900.
    int xb[2];
    #pragma unroll
    for (int k = 0; k < 2; ++k) {
        const int p = tid + k * 512;
        const int pc = p < 900 ? p : 899;   // dead slots clamp reads
        const int oh = pc / 30;
        xb[k] = oh * 32 + (pc - oh * 30);
    }

    float acc[2][16];
    #pragma unroll
    for (int k = 0; k < 2; ++k)
        #pragma unroll
        for (int oc = 0; oc < 16; ++oc) acc[k][oc] = 0.f;

    // Hot loop: dynamic ic, static (kh,kw). Weight indices are compile-time
    // offsets from the uniform pointer wq -> s_load/SGPR.
    #pragma unroll 1
    for (int ic = 0; ic < 3; ++ic) {
        const float* __restrict__ wq = w + ic * 9;
        const int xbase = ic << 10;          // ic*1024
        #pragma unroll
        for (int kh = 0; kh < 3; ++kh) {
            #pragma unroll
            for (int kw = 0; kw < 3; ++kw) {
                float ws[16];
                #pragma unroll
                for (int oc = 0; oc < 16; ++oc)
                    ws[oc] = wq[oc * 27 + kh * 3 + kw];   // uniform -> SGPR
                const int xoff = xbase + kh * 32 + kw;
                #pragma unroll
                for (int k = 0; k < 2; ++k) {
                    const float xv = sx[xoff + xb[k]];    // only LDS traffic
                    #pragma unroll
                    for (int oc = 0; oc < 16; ++oc)
                        acc[k][oc] = fmaf(xv, ws[oc], acc[k][oc]);
                }
            }
        }
    }

    // Bias via scalar path.
    float bb[16];
    #pragma unroll
    for (int oc = 0; oc < 16; ++oc) bb[oc] = bias[oc];

    // Epilogue: 4 chunks of 256 pixels. Writers of chunk c:
    //  c=0: p=tid,     tid in [0,256)    (acc[0])
    //  c=1: p=tid,     tid in [256,512)  (acc[0])
    //  c=2: p=tid+512, tid in [0,256)    (acc[1])
    //  c=3: p=tid+512, tid in [256,388)  (acc[1], 132 valid pixels)
    // Then all threads store sy as aligned float4 (full 64B lines).
    float* outn = out + (size_t)n * 14400;
    #pragma unroll
    for (int c = 0; c < 4; ++c) {
        __syncthreads();                    // sy free for reuse
        const int kk = c >> 1;
        if (((tid >> 8) == (c & 1)) && (c < 3 || tid < 388)) {
            const int col = tid & 255;
            #pragma unroll
            for (int oc = 0; oc < 16; ++oc) {
                const float y = acc[kk][oc] + bb[oc];
                // relu(y) * min(y+3,6)/6 == max(y,0) * min(y/6+0.5, 1)
                sy[oc * 256 + col] =
                    fmaxf(y, 0.f) * fminf(fmaf(y, 1.f / 6.f, 0.5f), 1.f);
            }
        }
        __syncthreads();
        // 16 oc rows x 64 float4 slots = 1024; 2 per thread.
        // Chunk 3 has 132 valid pixels per oc = exactly 33 float4s.
        const int lim4 = (c < 3) ? 64 : 33;
        #pragma unroll
        for (int i = 0; i < 2; ++i) {
            const int f = tid + i * 512;    // 0..1023
            const int oc = f >> 6;
            const int j = f & 63;
            if (j < lim4) {
                *(float4*)(outn + oc * 900 + c * 256 + 4 * j) =
                    *(const float4*)(sy + oc * 256 + 4 * j);
            }
        }
    }
}

extern "C" void kernel_launch(void* const* d_in, const int* in_sizes, int n_in,
                              void* d_out, int out_size, void* d_ws, size_t ws_size,
                              hipStream_t stream) {
    const float* x    = (const float*)d_in[0];
    const float* w    = (const float*)d_in[1];
    const float* bias = (const float*)d_in[2];
    float* out        = (float*)d_out;

    const int N = in_sizes[0] / (3 * 32 * 32);  // 4096
    conv3x3_hswish<<<N, 512, 0, stream>>>(x, w, bias, out);
}